// Round 1
// baseline (1202.939 us; speedup 1.0000x reference)
//
#include <hip/hip_runtime.h>
#include <math.h>

#define N   192
#define NN  (N * N)
#define NNN (N * N * N)

__device__ __forceinline__ int wrapN(int v) {
  if (v < 0)  v += N;
  if (v >= N) v -= N;
  return v;
}

__global__ void __launch_bounds__(256)
dem_forces_kernel(const float* __restrict__ xg,  const float* __restrict__ yg,
                  const float* __restrict__ zg,  const float* __restrict__ vxg,
                  const float* __restrict__ vyg, const float* __restrict__ vzg,
                  const float* __restrict__ dp,  float* __restrict__ out)
{
  const int tid = blockIdx.x * 256 + threadIdx.x;
  const int x = tid % N;
  const int t = tid / N;
  const int y = t % N;
  const int z = t / N;

  const float KN  = 500000.0f;
  const float EPS = 1e-4f;
  const float MU  = 0.5f;
  // ETA = 2*gamma*sqrt(KN*1.0); gamma = alpha/sqrt(alpha^2+1); alpha = -ln(0.7)/pi
  // computed in double so the float cast matches the Python-double constant exactly
  const double alpha_d = 0.35667494393873245 / 3.141592653589793;
  const float  ETA = (float)(2.0 * (alpha_d / sqrt(alpha_d * alpha_d + 1.0)) * sqrt(500000.0));

  const float two_d = 2.0f * dp[0];
  const float two2  = two_d * two_d;

  const float xc = xg[tid];
  const float yc = yg[tid];
  const float zc = zg[tid];

  float fxc = 0.f, fyc = 0.f, fzc = 0.f;
  float fxd = 0.f, fyd = 0.f, fzd = 0.f;

  // read index per axis for shift s = c-2 is (coord - s) mod N = coord + 2 - c
  int xi[5];
#pragma unroll
  for (int c = 0; c < 5; ++c) xi[c] = wrapN(x + 2 - c);

  for (int a = 0; a < 5; ++a) {          // s0 = a-2 (axis 0 = z here)
    const int zz = wrapN(z + 2 - a);
    const int zb = zz * N;
    for (int b = 0; b < 5; ++b) {        // s1 = b-2
      const int yy   = wrapN(y + 2 - b);
      const int rowb = (zb + yy) * N;
#pragma unroll
      for (int c = 0; c < 5; ++c) {      // s2 = c-2
        const int idx  = rowb + xi[c];
        const float dx = xc - xg[idx];
        const float dy = yc - yg[idx];
        const float dz = zc - zg[idx];
        const float d2 = dx * dx + dy * dy + dz * dz;
        // d2 < two2 is a superset of the reference overlap (dist < two_d);
        // exact mask recomputed inside. Rare: P(any lane) ~ 4e-5 per shift,
        // except the self-shift which contributes exact zeros.
        if (__any(d2 < two2)) {
          const float dist = sqrtf(d2);
          const bool  ov   = dist < two_d;
          const float safe = fmaxf(EPS, dist);
          const float coef = KN * (dist - two_d) / safe;
          fxc += ov ? coef * dx : 0.f;
          fyc += ov ? coef * dy : 0.f;
          fzc += ov ? coef * dz : 0.f;
          const float dvx = vxg[tid] - vxg[idx];
          const float dvy = vyg[tid] - vyg[idx];
          const float dvz = vzg[tid] - vzg[idx];
          const float vn  = (dvx * dx + dvy * dy + dvz * dz) / safe;
          const float evn = ETA * vn;
          fxd += ov ? (evn * dx) / safe : 0.f;
          fyd += ov ? (evn * dy) / safe : 0.f;
          fzd += ov ? (evn * dz) / safe : 0.f;
        }
      }
    }
  }

  // Friction: scan overwrites it each step -> only last shift (2,2,2) survives,
  // evaluated with the FINAL accumulated fxc..fzd. Non-overlap -> 0.
  float frx = 0.f, fry = 0.f, frz = 0.f;
  {
    const int idx  = (wrapN(z - 2) * N + wrapN(y - 2)) * N + xi[4];
    const float dx = xc - xg[idx];
    const float dy = yc - yg[idx];
    const float dz = zc - zg[idx];
    const float d2 = dx * dx + dy * dy + dz * dz;
    if (__any(d2 < two2)) {
      const float dist = sqrtf(d2);
      if (dist < two_d) {
        const float dvx = vxg[tid] - vxg[idx];
        const float dvy = vyg[tid] - vyg[idx];
        const float dvz = vzg[tid] - vzg[idx];
        frx = -(fabsf(fabsf(MU * fyc) + fabsf(MU * fzc) - MU * fxd) * dvx / fmaxf(EPS, fabsf(dvx)));
        fry = -(fabsf(fabsf(MU * fxc) + fabsf(MU * fzc) - MU * fyd) * dvy / fmaxf(EPS, fabsf(dvy)));
        // NB: reference uses dvy in the z-friction numerator (source bug kept)
        frz = -(fabsf(fabsf(MU * fxc) + fabsf(MU * fyc) - MU * fzd) * dvy / fmaxf(EPS, fabsf(dvz)));
      }
    }
  }

  out[0 * NNN + tid] = fxc;
  out[1 * NNN + tid] = fyc;
  out[2 * NNN + tid] = fzc;
  out[3 * NNN + tid] = fxd;
  out[4 * NNN + tid] = fyd;
  out[5 * NNN + tid] = fzd;
  out[6 * NNN + tid] = frx;
  out[7 * NNN + tid] = fry;
  out[8 * NNN + tid] = frz;
}

extern "C" void kernel_launch(void* const* d_in, const int* in_sizes, int n_in,
                              void* d_out, int out_size, void* d_ws, size_t ws_size,
                              hipStream_t stream) {
  const float* xg  = (const float*)d_in[0];
  const float* yg  = (const float*)d_in[1];
  const float* zg  = (const float*)d_in[2];
  const float* vxg = (const float*)d_in[3];
  const float* vyg = (const float*)d_in[4];
  const float* vzg = (const float*)d_in[5];
  const float* dp  = (const float*)d_in[6];
  float* out = (float*)d_out;

  dem_forces_kernel<<<NNN / 256, 256, 0, stream>>>(xg, yg, zg, vxg, vyg, vzg, dp, out);
}

// Round 2
// 602.850 us; speedup vs baseline: 1.9954x; 1.9954x over previous
//
#include <hip/hip_runtime.h>
#include <math.h>

#define N   192
#define NNN (N * N * N)
#define K   4            // cells per thread along x
#define XB  (N / K)      // 48 x-blocks per row

__device__ __forceinline__ int wrapN(int v) {
  if (v < 0)  v += N;
  if (v >= N) v -= N;
  return v;
}

__global__ void __launch_bounds__(256)
dem_forces_k4(const float* __restrict__ xg,  const float* __restrict__ yg,
              const float* __restrict__ zg,  const float* __restrict__ vxg,
              const float* __restrict__ vyg, const float* __restrict__ vzg,
              const float* __restrict__ dp,  float* __restrict__ out)
{
  const int t  = blockIdx.x * 256 + threadIdx.x;
  const int xb = t % XB;
  const int x0 = xb * K;
  const int r  = t / XB;
  const int y  = r % N;
  const int z  = r / N;

  const float KN  = 500000.0f;
  const float EPS = 1e-4f;
  const float MU  = 0.5f;
  const double alpha_d = 0.35667494393873245 / 3.141592653589793;
  const float  ETA = (float)(2.0 * (alpha_d / sqrt(alpha_d * alpha_d + 1.0)) * sqrt(500000.0));

  const float two_d = 2.0f * dp[0];
  const float two2  = two_d * two_d;
  const float two2m = two2 * 1.000002f;   // conservative wave-gate margin

  const int cellBase = (z * N + y) * N + x0;

  // center positions for the 4 owned cells (aligned float4)
  const float4 xc4 = *reinterpret_cast<const float4*>(xg + cellBase);
  const float4 yc4 = *reinterpret_cast<const float4*>(yg + cellBase);
  const float4 zc4 = *reinterpret_cast<const float4*>(zg + cellBase);
  const float xcv[K] = {xc4.x, xc4.y, xc4.z, xc4.w};
  const float ycv[K] = {yc4.x, yc4.y, yc4.z, yc4.w};
  const float zcv[K] = {zc4.x, zc4.y, zc4.z, zc4.w};

  // accumulators: [field][cell]  fields: fxc fyc fzc fxd fyd fzd
  float acc[6][K];
#pragma unroll
  for (int f = 0; f < 6; ++f)
#pragma unroll
    for (int c = 0; c < K; ++c) acc[f][c] = 0.0f;

  // 16B-aligned chunk starts covering x0-4 .. x0+7 (wrapped; 192%4==0 so a
  // chunk never crosses the row boundary)
  int cs[3];
  cs[0] = x0 - 4; if (cs[0] < 0)  cs[0] += N;
  cs[1] = x0;
  cs[2] = x0 + 4; if (cs[2] >= N) cs[2] -= N;

#pragma unroll 1
  for (int a = 0; a < 5; ++a) {          // z-shift: read zz = z+2-a
    const int zz = wrapN(z + 2 - a);
#pragma unroll 1
    for (int b = 0; b < 5; ++b) {        // y-shift: read yy = y+2-b
      const int yy   = wrapN(y + 2 - b);
      const int rowb = (zz * N + yy) * N;

      // stage neighbor row segment: 12 floats per array, registers only
      float nx[12], ny[12], nz[12];
#pragma unroll
      for (int j = 0; j < 3; ++j) {
        const float4 ax = *reinterpret_cast<const float4*>(xg + rowb + cs[j]);
        const float4 ay = *reinterpret_cast<const float4*>(yg + rowb + cs[j]);
        const float4 az = *reinterpret_cast<const float4*>(zg + rowb + cs[j]);
        nx[4*j+0] = ax.x; nx[4*j+1] = ax.y; nx[4*j+2] = ax.z; nx[4*j+3] = ax.w;
        ny[4*j+0] = ay.x; ny[4*j+1] = ay.y; ny[4*j+2] = ay.z; ny[4*j+3] = ay.w;
        nz[4*j+0] = az.x; nz[4*j+1] = az.y; nz[4*j+2] = az.z; nz[4*j+3] = az.w;
      }

      // fast path: min-d2 over the 4 cells x 5 x-offsets of this row
      float d2min = 1e30f;
#pragma unroll
      for (int c = 0; c < K; ++c) {
#pragma unroll
        for (int i = 0; i < 5; ++i) {
          const int p = c + 6 - i;       // stage index for x' = x0+c+2-i
          const float dx = xcv[c] - nx[p];
          const float dy = ycv[c] - ny[p];
          const float dz = zcv[c] - nz[p];
          const float d2 = dx*dx + dy*dy + dz*dz;
          d2min = fminf(d2min, d2);
        }
      }

      if (__any(d2min < two2m)) {
        // rare exact path (~500 overlap pairs in the whole grid)
#pragma unroll
        for (int c = 0; c < K; ++c) {
#pragma unroll
          for (int i = 0; i < 5; ++i) {
            const int p = c + 6 - i;
            const float dx = xcv[c] - nx[p];
            const float dy = ycv[c] - ny[p];
            const float dz = zcv[c] - nz[p];
            const float d2 = dx*dx + dy*dy + dz*dz;
            if (d2 < two2m) {
              const float dist = sqrtf(d2);
              const bool  ov   = dist < two_d;          // exact reference mask
              const float safe = fmaxf(EPS, dist);
              const float coef = KN * (dist - two_d) / safe;
              const int ci   = cellBase + c;
              const int nidx = rowb + wrapN(x0 + c + 2 - i);
              const float dvx = vxg[ci] - vxg[nidx];
              const float dvy = vyg[ci] - vyg[nidx];
              const float dvz = vzg[ci] - vzg[nidx];
              const float vn  = (dvx*dx + dvy*dy + dvz*dz) / safe;
              const float evn = ETA * vn;
              if (ov) {
                acc[0][c] += coef * dx;
                acc[1][c] += coef * dy;
                acc[2][c] += coef * dz;
                acc[3][c] += (evn * dx) / safe;
                acc[4][c] += (evn * dy) / safe;
                acc[5][c] += (evn * dz) / safe;
              }
            }
          }
        }
      }
    }
  }

  // friction: only the last scan shift (2,2,2) survives (read z-2,y-2,x-2),
  // evaluated against the FINAL accumulated fxc..fzd
  float frx[K], fry[K], frz[K];
#pragma unroll
  for (int c = 0; c < K; ++c) { frx[c] = 0.f; fry[c] = 0.f; frz[c] = 0.f; }
  {
    const int rowb = (wrapN(z - 2) * N + wrapN(y - 2)) * N;
    float d2v[K], dxv[K], dyv[K], dzv[K];
    float d2min = 1e30f;
#pragma unroll
    for (int c = 0; c < K; ++c) {
      const int nidx = rowb + wrapN(x0 + c - 2);
      const float dx = xcv[c] - xg[nidx];
      const float dy = ycv[c] - yg[nidx];
      const float dz = zcv[c] - zg[nidx];
      dxv[c] = dx; dyv[c] = dy; dzv[c] = dz;
      d2v[c] = dx*dx + dy*dy + dz*dz;
      d2min  = fminf(d2min, d2v[c]);
    }
    if (__any(d2min < two2m)) {
#pragma unroll
      for (int c = 0; c < K; ++c) {
        if (d2v[c] < two2m) {
          const float dist = sqrtf(d2v[c]);
          if (dist < two_d) {
            const int ci   = cellBase + c;
            const int nidx = rowb + wrapN(x0 + c - 2);
            const float dvx = vxg[ci] - vxg[nidx];
            const float dvy = vyg[ci] - vyg[nidx];
            const float dvz = vzg[ci] - vzg[nidx];
            frx[c] = -(fabsf(fabsf(MU*acc[1][c]) + fabsf(MU*acc[2][c]) - MU*acc[3][c])
                       * dvx / fmaxf(EPS, fabsf(dvx)));
            fry[c] = -(fabsf(fabsf(MU*acc[0][c]) + fabsf(MU*acc[2][c]) - MU*acc[4][c])
                       * dvy / fmaxf(EPS, fabsf(dvy)));
            // reference quirk: dvy in the z-friction numerator
            frz[c] = -(fabsf(fabsf(MU*acc[0][c]) + fabsf(MU*acc[1][c]) - MU*acc[5][c])
                       * dvy / fmaxf(EPS, fabsf(dvz)));
          }
        }
      }
    }
  }

  // 9 aligned float4 stores
#pragma unroll
  for (int f = 0; f < 6; ++f) {
    float4 o; o.x = acc[f][0]; o.y = acc[f][1]; o.z = acc[f][2]; o.w = acc[f][3];
    *reinterpret_cast<float4*>(out + f * NNN + cellBase) = o;
  }
  {
    float4 o;
    o.x = frx[0]; o.y = frx[1]; o.z = frx[2]; o.w = frx[3];
    *reinterpret_cast<float4*>(out + 6 * NNN + cellBase) = o;
    o.x = fry[0]; o.y = fry[1]; o.z = fry[2]; o.w = fry[3];
    *reinterpret_cast<float4*>(out + 7 * NNN + cellBase) = o;
    o.x = frz[0]; o.y = frz[1]; o.z = frz[2]; o.w = frz[3];
    *reinterpret_cast<float4*>(out + 8 * NNN + cellBase) = o;
  }
}

extern "C" void kernel_launch(void* const* d_in, const int* in_sizes, int n_in,
                              void* d_out, int out_size, void* d_ws, size_t ws_size,
                              hipStream_t stream) {
  const float* xg  = (const float*)d_in[0];
  const float* yg  = (const float*)d_in[1];
  const float* zg  = (const float*)d_in[2];
  const float* vxg = (const float*)d_in[3];
  const float* vyg = (const float*)d_in[4];
  const float* vzg = (const float*)d_in[5];
  const float* dp  = (const float*)d_in[6];
  float* out = (float*)d_out;

  const int threads = NNN / K;           // 1,769,472
  dem_forces_k4<<<threads / 256, 256, 0, stream>>>(xg, yg, zg, vxg, vyg, vzg, dp, out);
}

// Round 3
// 547.729 us; speedup vs baseline: 2.1962x; 1.1006x over previous
//
#include <hip/hip_runtime.h>
#include <math.h>

#define N   192
#define NNN (N * N * N)
#define K   4            // cells per thread along x
#define XB  (N / K)      // 48 x-blocks per row
#define NBLK (NNN / K / 256)   // 6912 blocks

__device__ __forceinline__ int wrapN(int v) {
  if (v < 0)  v += N;
  if (v >= N) v -= N;
  return v;
}

// rowbase for read-row (z+2-a, y+2-b); a,b uniform, z,y per-lane
#define ROWB(AA, BB, DST) do {                                          \
    int zz = z + 2 - (AA); if (zz >= N) zz -= N; if (zz < 0) zz += N;   \
    int yy = y + 2 - (BB); if (yy >= N) yy -= N; if (yy < 0) yy += N;   \
    DST = (zz * N + yy) * N; } while (0)

#define LOADROW(PX, PY, PZ, RB) do {                                    \
    const int _o0 = (RB) + cs0, _o1 = (RB) + cs1, _o2 = (RB) + cs2;     \
    PX[0] = *reinterpret_cast<const float4*>(xg + _o0);                 \
    PY[0] = *reinterpret_cast<const float4*>(yg + _o0);                 \
    PZ[0] = *reinterpret_cast<const float4*>(zg + _o0);                 \
    PX[1] = *reinterpret_cast<const float4*>(xg + _o1);                 \
    PY[1] = *reinterpret_cast<const float4*>(yg + _o1);                 \
    PZ[1] = *reinterpret_cast<const float4*>(zg + _o1);                 \
    PX[2] = *reinterpret_cast<const float4*>(xg + _o2);                 \
    PY[2] = *reinterpret_cast<const float4*>(yg + _o2);                 \
    PZ[2] = *reinterpret_cast<const float4*>(zg + _o2);                 \
  } while (0)

// Gate + rare path for one staged row. Gate only touches staged elems 2..9
// (p = c+6-i in [2,9]).  CENTER: exclude self pairs (i==2) from the gate OR —
// their contribution is an exact +/-0.0 no-op in the reference.
#define COMPUTE(PX, PY, PZ, ROWBV, CENTER) do {                              \
  const float ex[8] = {PX[0].z, PX[0].w, PX[1].x, PX[1].y,                   \
                       PX[1].z, PX[1].w, PX[2].x, PX[2].y};                  \
  const float ey[8] = {PY[0].z, PY[0].w, PY[1].x, PY[1].y,                   \
                       PY[1].z, PY[1].w, PY[2].x, PY[2].y};                  \
  const float ez[8] = {PZ[0].z, PZ[0].w, PZ[1].x, PZ[1].y,                   \
                       PZ[1].z, PZ[1].w, PZ[2].x, PZ[2].y};                  \
  unsigned uo = 0u, us = 0u;                                                 \
  _Pragma("unroll")                                                          \
  for (int c = 0; c < K; ++c) {                                              \
    _Pragma("unroll")                                                        \
    for (int i = 0; i < 5; ++i) {                                            \
      const int p = c + 4 - i;                                               \
      const float dx = xcv[c] - ex[p];                                       \
      const float dy = ycv[c] - ey[p];                                       \
      const float dz = zcv[c] - ez[p];                                       \
      const float tv = fmaf(dz, dz, fmaf(dy, dy, fmaf(dx, dx, negT)));       \
      if (i == 2) us |= __float_as_uint(tv);                                 \
      else        uo |= __float_as_uint(tv);                                 \
    }                                                                        \
  }                                                                          \
  const unsigned ug = (CENTER) ? uo : (uo | us);                             \
  if (__any((int)ug < 0)) {                                                  \
    _Pragma("unroll")                                                        \
    for (int c = 0; c < K; ++c) {                                            \
      _Pragma("unroll")                                                      \
      for (int i = 0; i < 5; ++i) {                                          \
        if ((CENTER) && i == 2) continue;                                    \
        const int p = c + 4 - i;                                             \
        const float dx = xcv[c] - ex[p];                                     \
        const float dy = ycv[c] - ey[p];                                     \
        const float dz = zcv[c] - ez[p];                                     \
        const float d2 = dx*dx + dy*dy + dz*dz;                              \
        if (d2 < two2m) {                                                    \
          const float dist = sqrtf(d2);                                      \
          const bool  ov   = dist < two_d;          /* exact reference mask */\
          const float safe = fmaxf(EPS, dist);                               \
          const float coef = KN * (dist - two_d) / safe;                     \
          const int ci   = cellBase + c;                                     \
          const int nidx = (ROWBV) + wrapN(x0 + c + 2 - i);                  \
          const float dvx = vxg[ci] - vxg[nidx];                             \
          const float dvy = vyg[ci] - vyg[nidx];                             \
          const float dvz = vzg[ci] - vzg[nidx];                             \
          const float vn  = (dvx*dx + dvy*dy + dvz*dz) / safe;               \
          const float evn = ETA * vn;                                        \
          if (ov) {                                                          \
            acc[0][c] += coef * dx;                                          \
            acc[1][c] += coef * dy;                                          \
            acc[2][c] += coef * dz;                                          \
            acc[3][c] += (evn * dx) / safe;                                  \
            acc[4][c] += (evn * dy) / safe;                                  \
            acc[5][c] += (evn * dz) / safe;                                  \
          }                                                                  \
        }                                                                    \
      }                                                                      \
    }                                                                        \
  }                                                                          \
} while (0)

__global__ void __launch_bounds__(256)
dem_forces_k4p(const float* __restrict__ xg,  const float* __restrict__ yg,
               const float* __restrict__ zg,  const float* __restrict__ vxg,
               const float* __restrict__ vyg, const float* __restrict__ vzg,
               const float* __restrict__ dp,  float* __restrict__ out)
{
  // T1 bijective XCD swizzle: 6912 % 8 == 0 -> each XCD owns a contiguous
  // z-slab (24 planes); z+-2 halo rows stay XCD-L2-local.
  const int bid  = (int)(blockIdx.x % 8u) * (NBLK / 8) + (int)(blockIdx.x / 8u);
  const int t    = bid * 256 + threadIdx.x;
  const int xb   = t % XB;
  const int x0   = xb * K;
  const int r    = t / XB;
  const int y    = r % N;
  const int z    = r / N;

  const float KN  = 500000.0f;
  const float EPS = 1e-4f;
  const float MU  = 0.5f;
  const double alpha_d = 0.35667494393873245 / 3.141592653589793;
  const float  ETA = (float)(2.0 * (alpha_d / sqrt(alpha_d*alpha_d + 1.0)) * sqrt(500000.0));

  const float two_d = 2.0f * dp[0];
  const float two2m = (two_d * two_d) * 1.000002f;  // conservative gate margin
  const float negT  = -two2m;

  const int cellBase = (z * N + y) * N + x0;

  const float4 xc4 = *reinterpret_cast<const float4*>(xg + cellBase);
  const float4 yc4 = *reinterpret_cast<const float4*>(yg + cellBase);
  const float4 zc4 = *reinterpret_cast<const float4*>(zg + cellBase);
  const float xcv[K] = {xc4.x, xc4.y, xc4.z, xc4.w};
  const float ycv[K] = {yc4.x, yc4.y, yc4.z, yc4.w};
  const float zcv[K] = {zc4.x, zc4.y, zc4.z, zc4.w};

  float acc[6][K];
#pragma unroll
  for (int f = 0; f < 6; ++f)
#pragma unroll
    for (int c = 0; c < K; ++c) acc[f][c] = 0.0f;

  int cs0 = x0 - 4; if (cs0 < 0) cs0 += N;
  const int cs1 = x0;
  int cs2 = x0 + 4; if (cs2 >= N) cs2 -= N;

  float4 Ax[3], Ay[3], Az[3], Bx[3], By[3], Bz[3];

  // software pipeline: prefetch row rr+1 while computing row rr
  int rb0, rb1;
  ROWB(0, 0, rb0);
  LOADROW(Ax, Ay, Az, rb0);

  int a = 0, b = 0;   // uniform (a,b) of current even row rr
#pragma unroll 1
  for (int rr = 0; rr < 24; rr += 2) {
    int a1 = a, b1 = b + 1; if (b1 == 5) { b1 = 0; ++a1; }
    ROWB(a1, b1, rb1);
    LOADROW(Bx, By, Bz, rb1);
    COMPUTE(Ax, Ay, Az, rb0, (rr == 12));

    int a2 = a1, b2 = b1 + 1; if (b2 == 5) { b2 = 0; ++a2; }
    int rb2; ROWB(a2, b2, rb2);
    LOADROW(Ax, Ay, Az, rb2);
    COMPUTE(Bx, By, Bz, rb1, false);

    rb0 = rb2; a = a2; b = b2;
  }
  COMPUTE(Ax, Ay, Az, rb0, false);   // row 24 (a=4,b=4)

  // friction: only the last scan shift (2,2,2) survives (reads z-2,y-2,x-2),
  // evaluated against the FINAL accumulated fxc..fzd
  float frx[K], fry[K], frz[K];
#pragma unroll
  for (int c = 0; c < K; ++c) { frx[c] = 0.f; fry[c] = 0.f; frz[c] = 0.f; }
  {
    const int rowb = (wrapN(z - 2) * N + wrapN(y - 2)) * N;
    float d2v[K], dxv[K], dyv[K], dzv[K];
    float d2min = 1e30f;
#pragma unroll
    for (int c = 0; c < K; ++c) {
      const int nidx = rowb + wrapN(x0 + c - 2);
      const float dx = xcv[c] - xg[nidx];
      const float dy = ycv[c] - yg[nidx];
      const float dz = zcv[c] - zg[nidx];
      dxv[c] = dx; dyv[c] = dy; dzv[c] = dz;
      d2v[c] = dx*dx + dy*dy + dz*dz;
      d2min  = fminf(d2min, d2v[c]);
    }
    if (__any(d2min < two2m)) {
#pragma unroll
      for (int c = 0; c < K; ++c) {
        if (d2v[c] < two2m) {
          const float dist = sqrtf(d2v[c]);
          if (dist < two_d) {
            const int ci   = cellBase + c;
            const int nidx = rowb + wrapN(x0 + c - 2);
            const float dvx = vxg[ci] - vxg[nidx];
            const float dvy = vyg[ci] - vyg[nidx];
            const float dvz = vzg[ci] - vzg[nidx];
            frx[c] = -(fabsf(fabsf(MU*acc[1][c]) + fabsf(MU*acc[2][c]) - MU*acc[3][c])
                       * dvx / fmaxf(EPS, fabsf(dvx)));
            fry[c] = -(fabsf(fabsf(MU*acc[0][c]) + fabsf(MU*acc[2][c]) - MU*acc[4][c])
                       * dvy / fmaxf(EPS, fabsf(dvy)));
            // reference quirk: dvy in the z-friction numerator
            frz[c] = -(fabsf(fabsf(MU*acc[0][c]) + fabsf(MU*acc[1][c]) - MU*acc[5][c])
                       * dvy / fmaxf(EPS, fabsf(dvz)));
          }
        }
      }
    }
  }

#pragma unroll
  for (int f = 0; f < 6; ++f) {
    float4 o; o.x = acc[f][0]; o.y = acc[f][1]; o.z = acc[f][2]; o.w = acc[f][3];
    *reinterpret_cast<float4*>(out + f * NNN + cellBase) = o;
  }
  {
    float4 o;
    o.x = frx[0]; o.y = frx[1]; o.z = frx[2]; o.w = frx[3];
    *reinterpret_cast<float4*>(out + 6 * NNN + cellBase) = o;
    o.x = fry[0]; o.y = fry[1]; o.z = fry[2]; o.w = fry[3];
    *reinterpret_cast<float4*>(out + 7 * NNN + cellBase) = o;
    o.x = frz[0]; o.y = frz[1]; o.z = frz[2]; o.w = frz[3];
    *reinterpret_cast<float4*>(out + 8 * NNN + cellBase) = o;
  }
}

extern "C" void kernel_launch(void* const* d_in, const int* in_sizes, int n_in,
                              void* d_out, int out_size, void* d_ws, size_t ws_size,
                              hipStream_t stream) {
  const float* xg  = (const float*)d_in[0];
  const float* yg  = (const float*)d_in[1];
  const float* zg  = (const float*)d_in[2];
  const float* vxg = (const float*)d_in[3];
  const float* vyg = (const float*)d_in[4];
  const float* vzg = (const float*)d_in[5];
  const float* dp  = (const float*)d_in[6];
  float* out = (float*)d_out;

  dem_forces_k4p<<<NBLK, 256, 0, stream>>>(xg, yg, zg, vxg, vyg, vzg, dp, out);
}

// Round 4
// 534.419 us; speedup vs baseline: 2.2509x; 1.0249x over previous
//
#include <hip/hip_runtime.h>
#include <math.h>

#define N   192
#define NNN (N * N * N)
#define K   4            // cells per thread along x
#define XB  (N / K)      // 48 x-blocks per row
#define NBLK (NNN / K / 256)   // 6912 blocks

typedef float f2 __attribute__((ext_vector_type(2)));

#if __has_builtin(__builtin_elementwise_fma)
#define PKFMA(a,b,c) __builtin_elementwise_fma((a),(b),(c))
#else
#define PKFMA(a,b,c) ((a)*(b)+(c))
#endif
#if __has_builtin(__builtin_elementwise_min)
#define PKMIN(a,b) __builtin_elementwise_min((a),(b))
#else
static __device__ __forceinline__ f2 pkmin_fb(f2 a, f2 b){ f2 r; r.x=fminf(a.x,b.x); r.y=fminf(a.y,b.y); return r; }
#define PKMIN(a,b) pkmin_fb((a),(b))
#endif

__device__ __forceinline__ int wrapN(int v) {
  if (v < 0)  v += N;
  if (v >= N) v -= N;
  return v;
}

// rowbase for read-row (z+2-a, y+2-b); a,b uniform, z,y per-lane
#define ROWB(AA, BB, DST) do {                                          \
    int zz = z + 2 - (AA); if (zz >= N) zz -= N; if (zz < 0) zz += N;   \
    int yy = y + 2 - (BB); if (yy >= N) yy -= N; if (yy < 0) yy += N;   \
    DST = (zz * N + yy) * N; } while (0)

#define LOADROW(PX, PY, PZ, RB) do {                                    \
    const int _o0 = (RB) + cs0, _o1 = (RB) + cs1, _o2 = (RB) + cs2;     \
    PX[0] = *reinterpret_cast<const float4*>(xg + _o0);                 \
    PY[0] = *reinterpret_cast<const float4*>(yg + _o0);                 \
    PZ[0] = *reinterpret_cast<const float4*>(zg + _o0);                 \
    PX[1] = *reinterpret_cast<const float4*>(xg + _o1);                 \
    PY[1] = *reinterpret_cast<const float4*>(yg + _o1);                 \
    PZ[1] = *reinterpret_cast<const float4*>(zg + _o1);                 \
    PX[2] = *reinterpret_cast<const float4*>(xg + _o2);                 \
    PY[2] = *reinterpret_cast<const float4*>(yg + _o2);                 \
    PZ[2] = *reinterpret_cast<const float4*>(zg + _o2);                 \
  } while (0)

// Packed-FP32 gate (cells 0-1 and 2-3 as float2 lanes) + pk_min reduction,
// then the identical-to-R3 scalar rare path (exact reference semantics).
// CENTER (runtime bool): self pairs (i==2) excluded from the gate value and
// skipped in the rare path — exact +/-0.0 no-ops in the reference.
#define COMPUTE(PX, PY, PZ, ROWBV, CENTER) do {                              \
  const float ex[8] = {PX[0].z, PX[0].w, PX[1].x, PX[1].y,                   \
                       PX[1].z, PX[1].w, PX[2].x, PX[2].y};                  \
  const float ey[8] = {PY[0].z, PY[0].w, PY[1].x, PY[1].y,                   \
                       PY[1].z, PY[1].w, PY[2].x, PY[2].y};                  \
  const float ez[8] = {PZ[0].z, PZ[0].w, PZ[1].x, PZ[1].y,                   \
                       PZ[1].z, PZ[1].w, PZ[2].x, PZ[2].y};                  \
  f2 m0 = {1e30f, 1e30f}, m1 = {1e30f, 1e30f};                               \
  f2 msf = {1e30f, 1e30f};                                                   \
  _Pragma("unroll")                                                          \
  for (int i = 0; i < 5; ++i) {                                              \
    const int p = 4 - i;                                                     \
    const f2 e0x = {ex[p],   ex[p+1]}, e1x = {ex[p+2], ex[p+3]};             \
    const f2 e0y = {ey[p],   ey[p+1]}, e1y = {ey[p+2], ey[p+3]};             \
    const f2 e0z = {ez[p],   ez[p+1]}, e1z = {ez[p+2], ez[p+3]};             \
    const f2 d0x = cx01 - e0x, d0y = cy01 - e0y, d0z = cz01 - e0z;           \
    const f2 d1x = cx23 - e1x, d1y = cy23 - e1y, d1z = cz23 - e1z;           \
    const f2 t0 = PKFMA(d0z, d0z, PKFMA(d0y, d0y, PKFMA(d0x, d0x, nT2)));    \
    const f2 t1 = PKFMA(d1z, d1z, PKFMA(d1y, d1y, PKFMA(d1x, d1x, nT2)));    \
    if (i == 2) { msf = PKMIN(msf, t0); msf = PKMIN(msf, t1); }              \
    else        { m0  = PKMIN(m0,  t0); m1  = PKMIN(m1,  t1); }              \
  }                                                                          \
  const f2 mo2 = PKMIN(m0, m1);                                              \
  const float mo = fminf(mo2.x, mo2.y);                                      \
  const float ms = fminf(msf.x, msf.y);                                      \
  const float mg = (CENTER) ? mo : fminf(mo, ms);                            \
  if (__any(mg < 0.0f)) {                                                    \
    _Pragma("unroll")                                                        \
    for (int c = 0; c < K; ++c) {                                            \
      _Pragma("unroll")                                                      \
      for (int i = 0; i < 5; ++i) {                                          \
        if (!((CENTER) && i == 2)) {                                         \
          const int p = c + 4 - i;                                           \
          const float dx = xcv[c] - ex[p];                                   \
          const float dy = ycv[c] - ey[p];                                   \
          const float dz = zcv[c] - ez[p];                                   \
          const float d2 = dx*dx + dy*dy + dz*dz;                            \
          if (d2 < two2m) {                                                  \
            const float dist = sqrtf(d2);                                    \
            const bool  ov   = dist < two_d;        /* exact reference mask */\
            const float safe = fmaxf(EPS, dist);                             \
            const float coef = KN * (dist - two_d) / safe;                   \
            const int ci   = cellBase + c;                                   \
            const int nidx = (ROWBV) + wrapN(x0 + c + 2 - i);                \
            const float dvx = vxg[ci] - vxg[nidx];                           \
            const float dvy = vyg[ci] - vyg[nidx];                           \
            const float dvz = vzg[ci] - vzg[nidx];                           \
            const float vn  = (dvx*dx + dvy*dy + dvz*dz) / safe;             \
            const float evn = ETA * vn;                                      \
            if (ov) {                                                        \
              acc[0][c] += coef * dx;                                        \
              acc[1][c] += coef * dy;                                        \
              acc[2][c] += coef * dz;                                        \
              acc[3][c] += (evn * dx) / safe;                                \
              acc[4][c] += (evn * dy) / safe;                                \
              acc[5][c] += (evn * dz) / safe;                                \
            }                                                                \
          }                                                                  \
        }                                                                    \
      }                                                                      \
    }                                                                        \
  }                                                                          \
} while (0)

__global__ void __launch_bounds__(256)
dem_forces_k4pk(const float* __restrict__ xg,  const float* __restrict__ yg,
                const float* __restrict__ zg,  const float* __restrict__ vxg,
                const float* __restrict__ vyg, const float* __restrict__ vzg,
                const float* __restrict__ dp,  float* __restrict__ out)
{
  // T1 bijective XCD swizzle: 6912 % 8 == 0 -> each XCD owns a contiguous
  // z-slab (24 planes); z+-2 halo rows stay XCD-L2-local. (R3: FETCH 322->101MB)
  const int bid  = (int)(blockIdx.x % 8u) * (NBLK / 8) + (int)(blockIdx.x / 8u);
  const int t    = bid * 256 + threadIdx.x;
  const int xb   = t % XB;
  const int x0   = xb * K;
  const int r    = t / XB;
  const int y    = r % N;
  const int z    = r / N;

  const float KN  = 500000.0f;
  const float EPS = 1e-4f;
  const float MU  = 0.5f;
  const double alpha_d = 0.35667494393873245 / 3.141592653589793;
  const float  ETA = (float)(2.0 * (alpha_d / sqrt(alpha_d*alpha_d + 1.0)) * sqrt(500000.0));

  const float two_d = 2.0f * dp[0];
  const float two2m = (two_d * two_d) * 1.000002f;  // conservative gate margin
  const float negT  = -two2m;
  const f2    nT2   = {negT, negT};

  const int cellBase = (z * N + y) * N + x0;

  const float4 xc4 = *reinterpret_cast<const float4*>(xg + cellBase);
  const float4 yc4 = *reinterpret_cast<const float4*>(yg + cellBase);
  const float4 zc4 = *reinterpret_cast<const float4*>(zg + cellBase);
  const float xcv[K] = {xc4.x, xc4.y, xc4.z, xc4.w};
  const float ycv[K] = {yc4.x, yc4.y, yc4.z, yc4.w};
  const float zcv[K] = {zc4.x, zc4.y, zc4.z, zc4.w};
  const f2 cx01 = {xc4.x, xc4.y}, cx23 = {xc4.z, xc4.w};
  const f2 cy01 = {yc4.x, yc4.y}, cy23 = {yc4.z, yc4.w};
  const f2 cz01 = {zc4.x, zc4.y}, cz23 = {zc4.z, zc4.w};

  float acc[6][K];
#pragma unroll
  for (int f = 0; f < 6; ++f)
#pragma unroll
    for (int c = 0; c < K; ++c) acc[f][c] = 0.0f;

  int cs0 = x0 - 4; if (cs0 < 0) cs0 += N;
  const int cs1 = x0;
  int cs2 = x0 + 4; if (cs2 >= N) cs2 -= N;

  float4 Ax[3], Ay[3], Az[3], Bx[3], By[3], Bz[3];

  // software pipeline: prefetch row rr+1 while computing row rr
  int rb0, rb1;
  ROWB(0, 0, rb0);
  LOADROW(Ax, Ay, Az, rb0);

  int a = 0, b = 0;   // uniform (a,b) of current even row rr
#pragma unroll 1
  for (int rr = 0; rr < 24; rr += 2) {
    int a1 = a, b1 = b + 1; if (b1 == 5) { b1 = 0; ++a1; }
    ROWB(a1, b1, rb1);
    LOADROW(Bx, By, Bz, rb1);
    COMPUTE(Ax, Ay, Az, rb0, (rr == 12));

    int a2 = a1, b2 = b1 + 1; if (b2 == 5) { b2 = 0; ++a2; }
    int rb2; ROWB(a2, b2, rb2);
    LOADROW(Ax, Ay, Az, rb2);
    COMPUTE(Bx, By, Bz, rb1, false);

    rb0 = rb2; a = a2; b = b2;
  }
  COMPUTE(Ax, Ay, Az, rb0, false);   // row 24 (a=4,b=4)

  // friction: only the last scan shift (2,2,2) survives (reads z-2,y-2,x-2),
  // evaluated against the FINAL accumulated fxc..fzd
  float frx[K], fry[K], frz[K];
#pragma unroll
  for (int c = 0; c < K; ++c) { frx[c] = 0.f; fry[c] = 0.f; frz[c] = 0.f; }
  {
    const int rowb = (wrapN(z - 2) * N + wrapN(y - 2)) * N;
    float d2v[K], dxv[K], dyv[K], dzv[K];
    float d2min = 1e30f;
#pragma unroll
    for (int c = 0; c < K; ++c) {
      const int nidx = rowb + wrapN(x0 + c - 2);
      const float dx = xcv[c] - xg[nidx];
      const float dy = ycv[c] - yg[nidx];
      const float dz = zcv[c] - zg[nidx];
      dxv[c] = dx; dyv[c] = dy; dzv[c] = dz;
      d2v[c] = dx*dx + dy*dy + dz*dz;
      d2min  = fminf(d2min, d2v[c]);
    }
    if (__any(d2min < two2m)) {
#pragma unroll
      for (int c = 0; c < K; ++c) {
        if (d2v[c] < two2m) {
          const float dist = sqrtf(d2v[c]);
          if (dist < two_d) {
            const int ci   = cellBase + c;
            const int nidx = rowb + wrapN(x0 + c - 2);
            const float dvx = vxg[ci] - vxg[nidx];
            const float dvy = vyg[ci] - vyg[nidx];
            const float dvz = vzg[ci] - vzg[nidx];
            frx[c] = -(fabsf(fabsf(MU*acc[1][c]) + fabsf(MU*acc[2][c]) - MU*acc[3][c])
                       * dvx / fmaxf(EPS, fabsf(dvx)));
            fry[c] = -(fabsf(fabsf(MU*acc[0][c]) + fabsf(MU*acc[2][c]) - MU*acc[4][c])
                       * dvy / fmaxf(EPS, fabsf(dvy)));
            // reference quirk: dvy in the z-friction numerator
            frz[c] = -(fabsf(fabsf(MU*acc[0][c]) + fabsf(MU*acc[1][c]) - MU*acc[5][c])
                       * dvy / fmaxf(EPS, fabsf(dvz)));
          }
        }
      }
    }
  }

#pragma unroll
  for (int f = 0; f < 6; ++f) {
    float4 o; o.x = acc[f][0]; o.y = acc[f][1]; o.z = acc[f][2]; o.w = acc[f][3];
    *reinterpret_cast<float4*>(out + f * NNN + cellBase) = o;
  }
  {
    float4 o;
    o.x = frx[0]; o.y = frx[1]; o.z = frx[2]; o.w = frx[3];
    *reinterpret_cast<float4*>(out + 6 * NNN + cellBase) = o;
    o.x = fry[0]; o.y = fry[1]; o.z = fry[2]; o.w = fry[3];
    *reinterpret_cast<float4*>(out + 7 * NNN + cellBase) = o;
    o.x = frz[0]; o.y = frz[1]; o.z = frz[2]; o.w = frz[3];
    *reinterpret_cast<float4*>(out + 8 * NNN + cellBase) = o;
  }
}

extern "C" void kernel_launch(void* const* d_in, const int* in_sizes, int n_in,
                              void* d_out, int out_size, void* d_ws, size_t ws_size,
                              hipStream_t stream) {
  const float* xg  = (const float*)d_in[0];
  const float* yg  = (const float*)d_in[1];
  const float* zg  = (const float*)d_in[2];
  const float* vxg = (const float*)d_in[3];
  const float* vyg = (const float*)d_in[4];
  const float* vzg = (const float*)d_in[5];
  const float* dp  = (const float*)d_in[6];
  float* out = (float*)d_out;

  dem_forces_k4pk<<<NBLK, 256, 0, stream>>>(xg, yg, zg, vxg, vyg, vzg, dp, out);
}